// Round 1
// baseline (1428.242 us; speedup 1.0000x reference)
//
#include <hip/hip_runtime.h>
#include <math.h>

#define NB 2
#define NT 4096
#define NC 512
#define NH 8
#define ND 64
#define N3C (3*NC)

// ---------------------------------------------------------------------------
// GEMM with bias: C[M,N] = A[M,K] @ B[K,N] + bias[N]
// 64x64 tile, BK=16, 256 threads, 4x4 per thread. fp32 (no fp32 MFMA on CDNA4).
// ---------------------------------------------------------------------------
__global__ __launch_bounds__(256) void gemm_bias_kernel(
    const float* __restrict__ A, const float* __restrict__ B,
    const float* __restrict__ bias, float* __restrict__ C,
    int M, int N, int K)
{
    __shared__ float As[16][65];   // transposed A tile: As[k][m], +1 pad
    __shared__ float Bs[16][64];   // Bs[k][n]

    const int tid = threadIdx.x;
    const int tx = tid & 15, ty = tid >> 4;
    const int r0 = ty << 2, c0 = tx << 2;
    const int m0 = blockIdx.y << 6, n0 = blockIdx.x << 6;
    // A tile loader: 64 rows x 16 k; each thread one float4
    const int ar = tid >> 2, ak = (tid & 3) << 2;
    // B tile loader: 16 rows x 64 n; each thread one float4
    const int br = tid >> 4, bc = (tid & 15) << 2;

    float acc[4][4] = {};

    for (int k0 = 0; k0 < K; k0 += 16) {
        float4 av = *(const float4*)(A + (size_t)(m0 + ar) * K + (k0 + ak));
        float4 bv = *(const float4*)(B + (size_t)(k0 + br) * N + (n0 + bc));
        __syncthreads();
        As[ak + 0][ar] = av.x;
        As[ak + 1][ar] = av.y;
        As[ak + 2][ar] = av.z;
        As[ak + 3][ar] = av.w;
        *(float4*)(&Bs[br][bc]) = bv;
        __syncthreads();
#pragma unroll
        for (int k = 0; k < 16; ++k) {
            const float a0 = As[k][r0 + 0];
            const float a1 = As[k][r0 + 1];
            const float a2 = As[k][r0 + 2];
            const float a3 = As[k][r0 + 3];
            const float4 bq = *(const float4*)(&Bs[k][c0]);
            acc[0][0] = fmaf(a0, bq.x, acc[0][0]); acc[0][1] = fmaf(a0, bq.y, acc[0][1]);
            acc[0][2] = fmaf(a0, bq.z, acc[0][2]); acc[0][3] = fmaf(a0, bq.w, acc[0][3]);
            acc[1][0] = fmaf(a1, bq.x, acc[1][0]); acc[1][1] = fmaf(a1, bq.y, acc[1][1]);
            acc[1][2] = fmaf(a1, bq.z, acc[1][2]); acc[1][3] = fmaf(a1, bq.w, acc[1][3]);
            acc[2][0] = fmaf(a2, bq.x, acc[2][0]); acc[2][1] = fmaf(a2, bq.y, acc[2][1]);
            acc[2][2] = fmaf(a2, bq.z, acc[2][2]); acc[2][3] = fmaf(a2, bq.w, acc[2][3]);
            acc[3][0] = fmaf(a3, bq.x, acc[3][0]); acc[3][1] = fmaf(a3, bq.y, acc[3][1]);
            acc[3][2] = fmaf(a3, bq.z, acc[3][2]); acc[3][3] = fmaf(a3, bq.w, acc[3][3]);
        }
    }

    const float4 bb = *(const float4*)(bias + n0 + c0);
#pragma unroll
    for (int i = 0; i < 4; ++i) {
        float4 cv = make_float4(acc[i][0] + bb.x, acc[i][1] + bb.y,
                                acc[i][2] + bb.z, acc[i][3] + bb.w);
        *(float4*)(C + (size_t)(m0 + r0 + i) * N + n0 + c0) = cv;
    }
}

// ---------------------------------------------------------------------------
// Causal flash attention, fp32. One block = 64 Q rows of one (b,h).
// qkv layout: [B, T, 3C]; q at col h*64, k at C + h*64, v at 2C + h*64.
// out layout: [B, T, C] (heads re-interleaved), ready for the proj GEMM.
// ---------------------------------------------------------------------------
__global__ __launch_bounds__(256) void attn_kernel(
    const float* __restrict__ qkv, float* __restrict__ out)
{
    __shared__ float Qs[64][68];   // stride 68 floats = 272 B: float4-aligned rows
    __shared__ float Ks[64][68];
    __shared__ float Vs[64][68];
    __shared__ float Ps[64][68];
    __shared__ float red[64][16];
    __shared__ float m_s[64], l_s[64], alpha_s[64];

    const int tid = threadIdx.x;
    const int tx = tid & 15, ty = tid >> 4;
    const int r0 = ty << 2, c0 = tx << 2;    // this thread's 4 rows / 4 cols
    const int qt = blockIdx.x;               // Q tile index, 0..63
    const int bh = blockIdx.y;               // 0..15
    const int b  = bh >> 3, h = bh & 7;
    const int qr0 = qt << 6;
    const size_t base = (size_t)b * NT * N3C;
    const int col = h * ND;

    // Load Q tile, pre-scaled by 1/sqrt(HD) = 0.125
    for (int f = tid; f < 1024; f += 256) {
        const int r = f >> 4, c = (f & 15) << 2;
        float4 v = *(const float4*)(qkv + base + (size_t)(qr0 + r) * N3C + col + c);
        Qs[r][c + 0] = v.x * 0.125f;
        Qs[r][c + 1] = v.y * 0.125f;
        Qs[r][c + 2] = v.z * 0.125f;
        Qs[r][c + 3] = v.w * 0.125f;
    }
    if (tid < 64) { m_s[tid] = -INFINITY; l_s[tid] = 0.0f; }

    float o[4][4] = {};

    for (int jt = 0; jt <= qt; ++jt) {
        const int kr0 = jt << 6;
        __syncthreads();   // (A) protect Ks/Vs/Ps from prior iter (and Q load, iter 0)
        for (int f = tid; f < 1024; f += 256) {
            const int r = f >> 4, c = (f & 15) << 2;
            const float* pk = qkv + base + (size_t)(kr0 + r) * N3C + NC + col + c;
            float4 kv = *(const float4*)pk;
            float4 vv = *(const float4*)(pk + NC);
            *(float4*)(&Ks[r][c]) = kv;
            *(float4*)(&Vs[r][c]) = vv;
        }
        __syncthreads();   // (B)

        // S = (Q * 1/8) K^T, 4x4 patch per thread
        float s[4][4] = {};
        for (int d = 0; d < 64; d += 4) {
            float4 qa0 = *(const float4*)(&Qs[r0 + 0][d]);
            float4 qa1 = *(const float4*)(&Qs[r0 + 1][d]);
            float4 qa2 = *(const float4*)(&Qs[r0 + 2][d]);
            float4 qa3 = *(const float4*)(&Qs[r0 + 3][d]);
            float4 kb0 = *(const float4*)(&Ks[c0 + 0][d]);
            float4 kb1 = *(const float4*)(&Ks[c0 + 1][d]);
            float4 kb2 = *(const float4*)(&Ks[c0 + 2][d]);
            float4 kb3 = *(const float4*)(&Ks[c0 + 3][d]);
#pragma unroll
            for (int i = 0; i < 4; ++i) {
                const float4 qa = (i == 0) ? qa0 : (i == 1) ? qa1 : (i == 2) ? qa2 : qa3;
#pragma unroll
                for (int j = 0; j < 4; ++j) {
                    const float4 kb = (j == 0) ? kb0 : (j == 1) ? kb1 : (j == 2) ? kb2 : kb3;
                    s[i][j] = fmaf(qa.x, kb.x, s[i][j]);
                    s[i][j] = fmaf(qa.y, kb.y, s[i][j]);
                    s[i][j] = fmaf(qa.z, kb.z, s[i][j]);
                    s[i][j] = fmaf(qa.w, kb.w, s[i][j]);
                }
            }
        }

        // Causal mask (only the diagonal tile has masked entries)
        if (jt == qt) {
#pragma unroll
            for (int i = 0; i < 4; ++i)
#pragma unroll
                for (int j = 0; j < 4; ++j)
                    if (c0 + j > r0 + i) s[i][j] = -INFINITY;
        }

        // Row-max: per-thread partial over 4 cols, tree over 16 threads/row
#pragma unroll
        for (int i = 0; i < 4; ++i) {
            red[r0 + i][tx] = fmaxf(fmaxf(s[i][0], s[i][1]), fmaxf(s[i][2], s[i][3]));
        }
        __syncthreads();   // (C)
        if (tid < 64) {
            float mx = red[tid][0];
#pragma unroll
            for (int q = 1; q < 16; ++q) mx = fmaxf(mx, red[tid][q]);
            const float mo = m_s[tid];
            const float mn = fmaxf(mo, mx);
            m_s[tid] = mn;
            alpha_s[tid] = __expf(mo - mn);   // exp(-inf)=0 on first tile
        }
        __syncthreads();   // (D)

        // P = exp(S - m); stage P in LDS; partial row sums
#pragma unroll
        for (int i = 0; i < 4; ++i) {
            const float mn = m_s[r0 + i];
            const float p0 = __expf(s[i][0] - mn);
            const float p1 = __expf(s[i][1] - mn);
            const float p2 = __expf(s[i][2] - mn);
            const float p3 = __expf(s[i][3] - mn);
            *(float4*)(&Ps[r0 + i][c0]) = make_float4(p0, p1, p2, p3);
            red[r0 + i][tx] = p0 + p1 + p2 + p3;
        }
        __syncthreads();   // (E)
        if (tid < 64) {
            float sm = 0.0f;
#pragma unroll
            for (int q = 0; q < 16; ++q) sm += red[tid][q];
            l_s[tid] = alpha_s[tid] * l_s[tid] + sm;
        }

        // O = alpha*O + P @ V
#pragma unroll
        for (int i = 0; i < 4; ++i) {
            const float al = alpha_s[r0 + i];
            o[i][0] *= al; o[i][1] *= al; o[i][2] *= al; o[i][3] *= al;
        }
        for (int c = 0; c < 64; c += 4) {
            float4 pr0 = *(const float4*)(&Ps[r0 + 0][c]);
            float4 pr1 = *(const float4*)(&Ps[r0 + 1][c]);
            float4 pr2 = *(const float4*)(&Ps[r0 + 2][c]);
            float4 pr3 = *(const float4*)(&Ps[r0 + 3][c]);
#pragma unroll
            for (int cc = 0; cc < 4; ++cc) {
                const float4 vv = *(const float4*)(&Vs[c + cc][c0]);
                const float p0 = (cc == 0) ? pr0.x : (cc == 1) ? pr0.y : (cc == 2) ? pr0.z : pr0.w;
                const float p1 = (cc == 0) ? pr1.x : (cc == 1) ? pr1.y : (cc == 2) ? pr1.z : pr1.w;
                const float p2 = (cc == 0) ? pr2.x : (cc == 1) ? pr2.y : (cc == 2) ? pr2.z : pr2.w;
                const float p3 = (cc == 0) ? pr3.x : (cc == 1) ? pr3.y : (cc == 2) ? pr3.z : pr3.w;
                o[0][0] = fmaf(p0, vv.x, o[0][0]); o[0][1] = fmaf(p0, vv.y, o[0][1]);
                o[0][2] = fmaf(p0, vv.z, o[0][2]); o[0][3] = fmaf(p0, vv.w, o[0][3]);
                o[1][0] = fmaf(p1, vv.x, o[1][0]); o[1][1] = fmaf(p1, vv.y, o[1][1]);
                o[1][2] = fmaf(p1, vv.z, o[1][2]); o[1][3] = fmaf(p1, vv.w, o[1][3]);
                o[2][0] = fmaf(p2, vv.x, o[2][0]); o[2][1] = fmaf(p2, vv.y, o[2][1]);
                o[2][2] = fmaf(p2, vv.z, o[2][2]); o[2][3] = fmaf(p2, vv.w, o[2][3]);
                o[3][0] = fmaf(p3, vv.x, o[3][0]); o[3][1] = fmaf(p3, vv.y, o[3][1]);
                o[3][2] = fmaf(p3, vv.z, o[3][2]); o[3][3] = fmaf(p3, vv.w, o[3][3]);
            }
        }
    }

    __syncthreads();  // ensure final l_s updates visible
#pragma unroll
    for (int i = 0; i < 4; ++i) {
        const float inv = 1.0f / l_s[r0 + i];
        float4 ov = make_float4(o[i][0] * inv, o[i][1] * inv, o[i][2] * inv, o[i][3] * inv);
        *(float4*)(out + ((size_t)b * NT + qr0 + r0 + i) * NC + col + c0) = ov;
    }
}

// ---------------------------------------------------------------------------
extern "C" void kernel_launch(void* const* d_in, const int* in_sizes, int n_in,
                              void* d_out, int out_size, void* d_ws, size_t ws_size,
                              hipStream_t stream)
{
    const float* x     = (const float*)d_in[0];
    const float* Wqkv  = (const float*)d_in[1];
    const float* bqkv  = (const float*)d_in[2];
    const float* Wproj = (const float*)d_in[3];
    const float* bproj = (const float*)d_in[4];
    float* out = (float*)d_out;

    // workspace: qkv [B,T,3C] fp32 (48 MB) + att [B,T,C] fp32 (16 MB)
    float* qkv = (float*)d_ws;
    float* att = qkv + (size_t)NB * NT * N3C;

    const dim3 blk(256);
    // x @ Wqkv + bqkv
    gemm_bias_kernel<<<dim3(N3C / 64, (NB * NT) / 64), blk, 0, stream>>>(
        x, Wqkv, bqkv, qkv, NB * NT, N3C, NC);
    // causal attention per (b, h)
    attn_kernel<<<dim3(NT / 64, NB * NH), blk, 0, stream>>>(qkv, att);
    // att @ Wproj + bproj
    gemm_bias_kernel<<<dim3(NC / 64, (NB * NT) / 64), blk, 0, stream>>>(
        att, Wproj, bproj, out, NB * NT, NC, NC);
}

// Round 2
// 632.607 us; speedup vs baseline: 2.2577x; 2.2577x over previous
//
#include <hip/hip_runtime.h>
#include <math.h>

#define NB 2
#define NT 4096
#define NC 512
#define NH 8
#define ND 64
#define N3C (3*NC)

typedef __attribute__((ext_vector_type(8))) __bf16 bf16x8;
typedef __attribute__((ext_vector_type(4))) __bf16 bf16x4;
typedef __attribute__((ext_vector_type(4))) float  f32x4;

// ---------------------------------------------------------------------------
// GEMM with bias: C[M,N] = A[M,K] @ B[K,N] + bias[N]  (fp32, unchanged R1)
// ---------------------------------------------------------------------------
__global__ __launch_bounds__(256) void gemm_bias_kernel(
    const float* __restrict__ A, const float* __restrict__ B,
    const float* __restrict__ bias, float* __restrict__ C,
    int M, int N, int K)
{
    __shared__ float As[16][65];
    __shared__ float Bs[16][64];

    const int tid = threadIdx.x;
    const int tx = tid & 15, ty = tid >> 4;
    const int r0 = ty << 2, c0 = tx << 2;
    const int m0 = blockIdx.y << 6, n0 = blockIdx.x << 6;
    const int ar = tid >> 2, ak = (tid & 3) << 2;
    const int br = tid >> 4, bc = (tid & 15) << 2;

    float acc[4][4] = {};

    for (int k0 = 0; k0 < K; k0 += 16) {
        float4 av = *(const float4*)(A + (size_t)(m0 + ar) * K + (k0 + ak));
        float4 bv = *(const float4*)(B + (size_t)(k0 + br) * N + (n0 + bc));
        __syncthreads();
        As[ak + 0][ar] = av.x;
        As[ak + 1][ar] = av.y;
        As[ak + 2][ar] = av.z;
        As[ak + 3][ar] = av.w;
        *(float4*)(&Bs[br][bc]) = bv;
        __syncthreads();
#pragma unroll
        for (int k = 0; k < 16; ++k) {
            const float a0 = As[k][r0 + 0];
            const float a1 = As[k][r0 + 1];
            const float a2 = As[k][r0 + 2];
            const float a3 = As[k][r0 + 3];
            const float4 bq = *(const float4*)(&Bs[k][c0]);
            acc[0][0] = fmaf(a0, bq.x, acc[0][0]); acc[0][1] = fmaf(a0, bq.y, acc[0][1]);
            acc[0][2] = fmaf(a0, bq.z, acc[0][2]); acc[0][3] = fmaf(a0, bq.w, acc[0][3]);
            acc[1][0] = fmaf(a1, bq.x, acc[1][0]); acc[1][1] = fmaf(a1, bq.y, acc[1][1]);
            acc[1][2] = fmaf(a1, bq.z, acc[1][2]); acc[1][3] = fmaf(a1, bq.w, acc[1][3]);
            acc[2][0] = fmaf(a2, bq.x, acc[2][0]); acc[2][1] = fmaf(a2, bq.y, acc[2][1]);
            acc[2][2] = fmaf(a2, bq.z, acc[2][2]); acc[2][3] = fmaf(a2, bq.w, acc[2][3]);
            acc[3][0] = fmaf(a3, bq.x, acc[3][0]); acc[3][1] = fmaf(a3, bq.y, acc[3][1]);
            acc[3][2] = fmaf(a3, bq.z, acc[3][2]); acc[3][3] = fmaf(a3, bq.w, acc[3][3]);
        }
    }

    const float4 bb = *(const float4*)(bias + n0 + c0);
#pragma unroll
    for (int i = 0; i < 4; ++i) {
        float4 cv = make_float4(acc[i][0] + bb.x, acc[i][1] + bb.y,
                                acc[i][2] + bb.z, acc[i][3] + bb.w);
        *(float4*)(C + (size_t)(m0 + r0 + i) * N + n0 + c0) = cv;
    }
}

// ---------------------------------------------------------------------------
// Causal flash attention, bf16 MFMA (16x16x32), fp32 accumulate/softmax.
// One block = 64 Q rows of one (b,h); wave w owns S/O rows [16w, 16w+16).
// C/D layout: col = lane&15, row = (lane>>4)*4 + reg  [m89-verified].
// A layout:   m = lane&15,  k = (lane>>4)*8 + j.
// B layout:   n = lane&15,  k = (lane>>4)*8 + j  (B[k][n] = operand^T rows).
// ---------------------------------------------------------------------------
__global__ __launch_bounds__(256) void attn_kernel(
    const float* __restrict__ qkv, float* __restrict__ out)
{
    __shared__ __bf16 Qs[64][72];   // [q-row][d]   stride 144 B (16B-aligned rows)
    __shared__ __bf16 Ks[64][72];   // [k-row][d]
    __shared__ __bf16 Vt[64][72];   // [d][k-row]   (transposed V)
    __shared__ __bf16 Ps[64][72];   // [q-row][k-row]

    const int tid  = threadIdx.x;
    const int qt   = 63 - blockIdx.x;          // big (diagonal-heavy) blocks first
    const int bh   = blockIdx.y;
    const int b    = bh >> 3, h = bh & 7;
    const int qr0  = qt << 6;
    const size_t base = (size_t)b * NT * N3C;
    const int col  = h * ND;

    const int w    = tid >> 6;                 // wave 0..3
    const int lane = tid & 63;
    const int g    = lane >> 4;                // 4-lane-group row block
    const int n    = lane & 15;                // column-within-tile / A-row
    const int rb   = w << 4;                   // wave's first row (local)

    // ---- stage Q (pre-scaled by 1/sqrt(64)=0.125), fp32->bf16 ----
    for (int f = tid; f < 1024; f += 256) {
        const int r = f >> 4, c = (f & 15) << 2;
        float4 v = *(const float4*)(qkv + base + (size_t)(qr0 + r) * N3C + col + c);
        bf16x4 q;
        q[0] = (__bf16)(v.x * 0.125f);
        q[1] = (__bf16)(v.y * 0.125f);
        q[2] = (__bf16)(v.z * 0.125f);
        q[3] = (__bf16)(v.w * 0.125f);
        *(bf16x4*)&Qs[r][c] = q;
    }
    __syncthreads();

    // Q A-fragments are loop-invariant: hoist
    const bf16x8 qf0 = *(const bf16x8*)&Qs[rb + n][(g << 3)];
    const bf16x8 qf1 = *(const bf16x8*)&Qs[rb + n][32 + (g << 3)];

    f32x4 O[4] = {{0.f,0.f,0.f,0.f},{0.f,0.f,0.f,0.f},{0.f,0.f,0.f,0.f},{0.f,0.f,0.f,0.f}};
    float m_i[4] = {-INFINITY, -INFINITY, -INFINITY, -INFINITY};
    float l_i[4] = {0.f, 0.f, 0.f, 0.f};

    for (int jt = 0; jt <= qt; ++jt) {
        const int kr0 = jt << 6;
        __syncthreads();   // all waves done reading Ks/Vt of previous tile
        for (int f = tid; f < 1024; f += 256) {
            const int r = f >> 4, c = (f & 15) << 2;
            const float* pk = qkv + base + (size_t)(kr0 + r) * N3C + NC + col + c;
            float4 kv = *(const float4*)pk;
            float4 vv = *(const float4*)(pk + NC);
            bf16x4 kq;
            kq[0] = (__bf16)kv.x; kq[1] = (__bf16)kv.y;
            kq[2] = (__bf16)kv.z; kq[3] = (__bf16)kv.w;
            *(bf16x4*)&Ks[r][c] = kq;
            Vt[c + 0][r] = (__bf16)vv.x;
            Vt[c + 1][r] = (__bf16)vv.y;
            Vt[c + 2][r] = (__bf16)vv.z;
            Vt[c + 3][r] = (__bf16)vv.w;
        }
        __syncthreads();

        // ---- S = Q K^T : 4 j-tiles x 2 k-steps per wave ----
        f32x4 S[4];
#pragma unroll
        for (int t = 0; t < 4; ++t) {
            const bf16x8 k0 = *(const bf16x8*)&Ks[(t << 4) + n][(g << 3)];
            const bf16x8 k1 = *(const bf16x8*)&Ks[(t << 4) + n][32 + (g << 3)];
            f32x4 acc = {0.f, 0.f, 0.f, 0.f};
            acc = __builtin_amdgcn_mfma_f32_16x16x32_bf16(qf0, k0, acc, 0, 0, 0);
            acc = __builtin_amdgcn_mfma_f32_16x16x32_bf16(qf1, k1, acc, 0, 0, 0);
            S[t] = acc;
        }

        // ---- causal mask (diagonal tile only) ----
        if (jt == qt) {
#pragma unroll
            for (int t = 0; t < 4; ++t)
#pragma unroll
                for (int reg = 0; reg < 4; ++reg)
                    if ((t << 4) + n > rb + (g << 2) + reg) S[t][reg] = -INFINITY;
        }

        // ---- online softmax, all in registers ----
        float mnew[4], alpha[4], rsum[4];
#pragma unroll
        for (int reg = 0; reg < 4; ++reg) {
            float mx = fmaxf(fmaxf(S[0][reg], S[1][reg]), fmaxf(S[2][reg], S[3][reg]));
            mx = fmaxf(mx, __shfl_xor(mx, 1));
            mx = fmaxf(mx, __shfl_xor(mx, 2));
            mx = fmaxf(mx, __shfl_xor(mx, 4));
            mx = fmaxf(mx, __shfl_xor(mx, 8));
            mnew[reg]  = fmaxf(m_i[reg], mx);
            alpha[reg] = __expf(m_i[reg] - mnew[reg]);   // exp(-inf)=0 first tile
            m_i[reg]   = mnew[reg];
            rsum[reg]  = 0.f;
        }
#pragma unroll
        for (int t = 0; t < 4; ++t)
#pragma unroll
            for (int reg = 0; reg < 4; ++reg) {
                const float p = __expf(S[t][reg] - mnew[reg]);
                S[t][reg] = p;
                rsum[reg] += p;
            }
        // stage P (C-layout -> LDS) for A-operand reload; same-wave rows only,
        // so no barrier needed (compiler orders via lgkmcnt on Ps aliasing)
#pragma unroll
        for (int t = 0; t < 4; ++t)
#pragma unroll
            for (int reg = 0; reg < 4; ++reg)
                Ps[rb + (g << 2) + reg][(t << 4) + n] = (__bf16)S[t][reg];
#pragma unroll
        for (int reg = 0; reg < 4; ++reg) {
            float sm = rsum[reg];
            sm += __shfl_xor(sm, 1);
            sm += __shfl_xor(sm, 2);
            sm += __shfl_xor(sm, 4);
            sm += __shfl_xor(sm, 8);
            l_i[reg] = alpha[reg] * l_i[reg] + sm;
        }
#pragma unroll
        for (int t = 0; t < 4; ++t)
#pragma unroll
            for (int reg = 0; reg < 4; ++reg)
                O[t][reg] *= alpha[reg];

        // ---- O += P V : P as A-operand, Vt rows as B-operand ----
        const bf16x8 p0 = *(const bf16x8*)&Ps[rb + n][(g << 3)];
        const bf16x8 p1 = *(const bf16x8*)&Ps[rb + n][32 + (g << 3)];
#pragma unroll
        for (int t = 0; t < 4; ++t) {
            const bf16x8 v0 = *(const bf16x8*)&Vt[(t << 4) + n][(g << 3)];
            const bf16x8 v1 = *(const bf16x8*)&Vt[(t << 4) + n][32 + (g << 3)];
            O[t] = __builtin_amdgcn_mfma_f32_16x16x32_bf16(p0, v0, O[t], 0, 0, 0);
            O[t] = __builtin_amdgcn_mfma_f32_16x16x32_bf16(p1, v1, O[t], 0, 0, 0);
        }
    }

    // ---- epilogue: normalize and store (fp32) ----
#pragma unroll
    for (int reg = 0; reg < 4; ++reg) {
        const float inv = 1.0f / l_i[reg];
        const size_t row = (size_t)b * NT + qr0 + rb + (g << 2) + reg;
#pragma unroll
        for (int t = 0; t < 4; ++t)
            out[row * NC + col + (t << 4) + n] = O[t][reg] * inv;
    }
}

// ---------------------------------------------------------------------------
extern "C" void kernel_launch(void* const* d_in, const int* in_sizes, int n_in,
                              void* d_out, int out_size, void* d_ws, size_t ws_size,
                              hipStream_t stream)
{
    const float* x     = (const float*)d_in[0];
    const float* Wqkv  = (const float*)d_in[1];
    const float* bqkv  = (const float*)d_in[2];
    const float* Wproj = (const float*)d_in[3];
    const float* bproj = (const float*)d_in[4];
    float* out = (float*)d_out;

    float* qkv = (float*)d_ws;                         // [B,T,3C] fp32
    float* att = qkv + (size_t)NB * NT * N3C;          // [B,T,C]  fp32

    const dim3 blk(256);
    gemm_bias_kernel<<<dim3(N3C / 64, (NB * NT) / 64), blk, 0, stream>>>(
        x, Wqkv, bqkv, qkv, NB * NT, N3C, NC);
    attn_kernel<<<dim3(NT / 64, NB * NH), blk, 0, stream>>>(qkv, att);
    gemm_bias_kernel<<<dim3(NC / 64, (NB * NT) / 64), blk, 0, stream>>>(
        att, Wproj, bproj, out, NB * NT, NC, NC);
}

// Round 3
// 560.189 us; speedup vs baseline: 2.5496x; 1.1293x over previous
//
#include <hip/hip_runtime.h>
#include <math.h>

#define NB 2
#define NT 4096
#define NC 512
#define NH 8
#define ND 64
#define N3C (3*NC)

typedef __attribute__((ext_vector_type(8))) __bf16 bf16x8;
typedef __attribute__((ext_vector_type(4))) __bf16 bf16x4;
typedef __attribute__((ext_vector_type(4))) float  f32x4;

// ---------------------------------------------------------------------------
// GEMM with bias: C[M,N] = A[M,K] @ B[K,N] + bias[N]  (fp32, unchanged)
// ---------------------------------------------------------------------------
__global__ __launch_bounds__(256) void gemm_bias_kernel(
    const float* __restrict__ A, const float* __restrict__ B,
    const float* __restrict__ bias, float* __restrict__ C,
    int M, int N, int K)
{
    __shared__ float As[16][65];
    __shared__ float Bs[16][64];

    const int tid = threadIdx.x;
    const int tx = tid & 15, ty = tid >> 4;
    const int r0 = ty << 2, c0 = tx << 2;
    const int m0 = blockIdx.y << 6, n0 = blockIdx.x << 6;
    const int ar = tid >> 2, ak = (tid & 3) << 2;
    const int br = tid >> 4, bc = (tid & 15) << 2;

    float acc[4][4] = {};

    for (int k0 = 0; k0 < K; k0 += 16) {
        float4 av = *(const float4*)(A + (size_t)(m0 + ar) * K + (k0 + ak));
        float4 bv = *(const float4*)(B + (size_t)(k0 + br) * N + (n0 + bc));
        __syncthreads();
        As[ak + 0][ar] = av.x;
        As[ak + 1][ar] = av.y;
        As[ak + 2][ar] = av.z;
        As[ak + 3][ar] = av.w;
        *(float4*)(&Bs[br][bc]) = bv;
        __syncthreads();
#pragma unroll
        for (int k = 0; k < 16; ++k) {
            const float a0 = As[k][r0 + 0];
            const float a1 = As[k][r0 + 1];
            const float a2 = As[k][r0 + 2];
            const float a3 = As[k][r0 + 3];
            const float4 bq = *(const float4*)(&Bs[k][c0]);
            acc[0][0] = fmaf(a0, bq.x, acc[0][0]); acc[0][1] = fmaf(a0, bq.y, acc[0][1]);
            acc[0][2] = fmaf(a0, bq.z, acc[0][2]); acc[0][3] = fmaf(a0, bq.w, acc[0][3]);
            acc[1][0] = fmaf(a1, bq.x, acc[1][0]); acc[1][1] = fmaf(a1, bq.y, acc[1][1]);
            acc[1][2] = fmaf(a1, bq.z, acc[1][2]); acc[1][3] = fmaf(a1, bq.w, acc[1][3]);
            acc[2][0] = fmaf(a2, bq.x, acc[2][0]); acc[2][1] = fmaf(a2, bq.y, acc[2][1]);
            acc[2][2] = fmaf(a2, bq.z, acc[2][2]); acc[2][3] = fmaf(a2, bq.w, acc[2][3]);
            acc[3][0] = fmaf(a3, bq.x, acc[3][0]); acc[3][1] = fmaf(a3, bq.y, acc[3][1]);
            acc[3][2] = fmaf(a3, bq.z, acc[3][2]); acc[3][3] = fmaf(a3, bq.w, acc[3][3]);
        }
    }

    const float4 bb = *(const float4*)(bias + n0 + c0);
#pragma unroll
    for (int i = 0; i < 4; ++i) {
        float4 cv = make_float4(acc[i][0] + bb.x, acc[i][1] + bb.y,
                                acc[i][2] + bb.z, acc[i][3] + bb.w);
        *(float4*)(C + (size_t)(m0 + r0 + i) * N + n0 + c0) = cv;
    }
}

// ---------------------------------------------------------------------------
// Causal flash attention, bf16 MFMA 16x16x32, fp32 softmax state.
// R3: register-prefetch of next K/V tile across compute; row-sum via P*ones
// MFMA; Ps aliased onto Qs (Q fragments hoisted before first barrier).
// ---------------------------------------------------------------------------
__global__ __launch_bounds__(256) void attn_kernel(
    const float* __restrict__ qkv, float* __restrict__ out)
{
    __shared__ __bf16 QPs[64][72];  // Q tile, then reused as P tile
    __shared__ __bf16 Ks[64][72];   // [k-row][d]
    __shared__ __bf16 Vt[64][72];   // [d][k-row] (transposed V)

    const int tid  = threadIdx.x;
    const int qt   = 63 - blockIdx.x;          // diagonal-heavy blocks first
    const int bh   = blockIdx.y;
    const int b    = bh >> 3, h = bh & 7;
    const int qr0  = qt << 6;
    const size_t base = (size_t)b * NT * N3C;
    const int col  = h * ND;

    const int w    = tid >> 6;
    const int lane = tid & 63;
    const int g    = lane >> 4;
    const int n    = lane & 15;
    const int rb   = w << 4;

    // staging geometry: thread covers rows rs+16i (i=0..3), cols cs..cs+3
    const int rs = tid >> 4;
    const int cs = (tid & 15) << 2;
    const float* kbase = qkv + base + NC + col + cs;

    // ---- stage Q (pre-scaled by 0.125), fp32->bf16 ----
#pragma unroll
    for (int i = 0; i < 4; ++i) {
        const int r = rs + (i << 4);
        float4 v = *(const float4*)(qkv + base + (size_t)(qr0 + r) * N3C + col + cs);
        bf16x4 q;
        q[0] = (__bf16)(v.x * 0.125f);
        q[1] = (__bf16)(v.y * 0.125f);
        q[2] = (__bf16)(v.z * 0.125f);
        q[3] = (__bf16)(v.w * 0.125f);
        *(bf16x4*)&QPs[r][cs] = q;
    }
    __syncthreads();

    const bf16x8 qf0 = *(const bf16x8*)&QPs[rb + n][(g << 3)];
    const bf16x8 qf1 = *(const bf16x8*)&QPs[rb + n][32 + (g << 3)];

    bf16x8 ones;
#pragma unroll
    for (int j = 0; j < 8; ++j) ones[j] = (__bf16)1.0f;

    f32x4 O[4] = {{0.f,0.f,0.f,0.f},{0.f,0.f,0.f,0.f},{0.f,0.f,0.f,0.f},{0.f,0.f,0.f,0.f}};
    float m_i[4] = {-INFINITY, -INFINITY, -INFINITY, -INFINITY};
    float l_i[4] = {0.f, 0.f, 0.f, 0.f};

    // ---- preload tile 0 K/V into registers ----
    float4 kreg[4], vreg[4];
#pragma unroll
    for (int i = 0; i < 4; ++i) {
        const float* p = kbase + (size_t)(rs + (i << 4)) * N3C;
        kreg[i] = *(const float4*)p;
        vreg[i] = *(const float4*)(p + NC);
    }

    for (int jt = 0; jt <= qt; ++jt) {
        __syncthreads();   // all waves done reading Ks/Vt (and QPs frags, iter 0)

        // write prefetched regs -> LDS (cvt to bf16; V transposed)
#pragma unroll
        for (int i = 0; i < 4; ++i) {
            const int r = rs + (i << 4);
            bf16x4 kq;
            kq[0] = (__bf16)kreg[i].x; kq[1] = (__bf16)kreg[i].y;
            kq[2] = (__bf16)kreg[i].z; kq[3] = (__bf16)kreg[i].w;
            *(bf16x4*)&Ks[r][cs] = kq;
            Vt[cs + 0][r] = (__bf16)vreg[i].x;
            Vt[cs + 1][r] = (__bf16)vreg[i].y;
            Vt[cs + 2][r] = (__bf16)vreg[i].z;
            Vt[cs + 3][r] = (__bf16)vreg[i].w;
        }
        __syncthreads();

        // issue prefetch for next tile; lands before next iter's LDS write
        if (jt < qt) {
            const int kr1 = (jt + 1) << 6;
#pragma unroll
            for (int i = 0; i < 4; ++i) {
                const float* p = kbase + (size_t)(kr1 + rs + (i << 4)) * N3C;
                kreg[i] = *(const float4*)p;
                vreg[i] = *(const float4*)(p + NC);
            }
        }

        // ---- S = Q K^T ----
        f32x4 S[4];
#pragma unroll
        for (int t = 0; t < 4; ++t) {
            const bf16x8 k0 = *(const bf16x8*)&Ks[(t << 4) + n][(g << 3)];
            const bf16x8 k1 = *(const bf16x8*)&Ks[(t << 4) + n][32 + (g << 3)];
            f32x4 acc = {0.f, 0.f, 0.f, 0.f};
            acc = __builtin_amdgcn_mfma_f32_16x16x32_bf16(qf0, k0, acc, 0, 0, 0);
            acc = __builtin_amdgcn_mfma_f32_16x16x32_bf16(qf1, k1, acc, 0, 0, 0);
            S[t] = acc;
        }

        // ---- causal mask (diagonal tile only) ----
        if (jt == qt) {
#pragma unroll
            for (int t = 0; t < 4; ++t)
#pragma unroll
                for (int reg = 0; reg < 4; ++reg)
                    if ((t << 4) + n > rb + (g << 2) + reg) S[t][reg] = -INFINITY;
        }

        // ---- online softmax (row-max via shuffles; row-sum via MFMA later) ----
        float mnew[4], alpha[4];
#pragma unroll
        for (int reg = 0; reg < 4; ++reg) {
            float mx = fmaxf(fmaxf(S[0][reg], S[1][reg]), fmaxf(S[2][reg], S[3][reg]));
            mx = fmaxf(mx, __shfl_xor(mx, 1));
            mx = fmaxf(mx, __shfl_xor(mx, 2));
            mx = fmaxf(mx, __shfl_xor(mx, 4));
            mx = fmaxf(mx, __shfl_xor(mx, 8));
            mnew[reg]  = fmaxf(m_i[reg], mx);
            alpha[reg] = __expf(m_i[reg] - mnew[reg]);
            m_i[reg]   = mnew[reg];
        }
#pragma unroll
        for (int t = 0; t < 4; ++t)
#pragma unroll
            for (int reg = 0; reg < 4; ++reg)
                S[t][reg] = __expf(S[t][reg] - mnew[reg]);

        // stage P (C-layout -> LDS, same-wave rows only: no barrier needed)
#pragma unroll
        for (int t = 0; t < 4; ++t)
#pragma unroll
            for (int reg = 0; reg < 4; ++reg)
                QPs[rb + (g << 2) + reg][(t << 4) + n] = (__bf16)S[t][reg];

#pragma unroll
        for (int t = 0; t < 4; ++t)
#pragma unroll
            for (int reg = 0; reg < 4; ++reg)
                O[t][reg] *= alpha[reg];

        // ---- O += P V ; l += P * ones (row-sum from the matrix pipe) ----
        const bf16x8 p0 = *(const bf16x8*)&QPs[rb + n][(g << 3)];
        const bf16x8 p1 = *(const bf16x8*)&QPs[rb + n][32 + (g << 3)];
        f32x4 Lacc = {0.f, 0.f, 0.f, 0.f};
        Lacc = __builtin_amdgcn_mfma_f32_16x16x32_bf16(p0, ones, Lacc, 0, 0, 0);
        Lacc = __builtin_amdgcn_mfma_f32_16x16x32_bf16(p1, ones, Lacc, 0, 0, 0);
#pragma unroll
        for (int t = 0; t < 4; ++t) {
            const bf16x8 v0 = *(const bf16x8*)&Vt[(t << 4) + n][(g << 3)];
            const bf16x8 v1 = *(const bf16x8*)&Vt[(t << 4) + n][32 + (g << 3)];
            O[t] = __builtin_amdgcn_mfma_f32_16x16x32_bf16(p0, v0, O[t], 0, 0, 0);
            O[t] = __builtin_amdgcn_mfma_f32_16x16x32_bf16(p1, v1, O[t], 0, 0, 0);
        }
#pragma unroll
        for (int reg = 0; reg < 4; ++reg)
            l_i[reg] = alpha[reg] * l_i[reg] + Lacc[reg];
    }

    // ---- epilogue ----
#pragma unroll
    for (int reg = 0; reg < 4; ++reg) {
        const float inv = 1.0f / l_i[reg];
        const size_t row = (size_t)b * NT + qr0 + rb + (g << 2) + reg;
#pragma unroll
        for (int t = 0; t < 4; ++t)
            out[row * NC + col + (t << 4) + n] = O[t][reg] * inv;
    }
}

// ---------------------------------------------------------------------------
extern "C" void kernel_launch(void* const* d_in, const int* in_sizes, int n_in,
                              void* d_out, int out_size, void* d_ws, size_t ws_size,
                              hipStream_t stream)
{
    const float* x     = (const float*)d_in[0];
    const float* Wqkv  = (const float*)d_in[1];
    const float* bqkv  = (const float*)d_in[2];
    const float* Wproj = (const float*)d_in[3];
    const float* bproj = (const float*)d_in[4];
    float* out = (float*)d_out;

    float* qkv = (float*)d_ws;                         // [B,T,3C] fp32
    float* att = qkv + (size_t)NB * NT * N3C;          // [B,T,C]  fp32

    const dim3 blk(256);
    gemm_bias_kernel<<<dim3(N3C / 64, (NB * NT) / 64), blk, 0, stream>>>(
        x, Wqkv, bqkv, qkv, NB * NT, N3C, NC);
    attn_kernel<<<dim3(NT / 64, NB * NH), blk, 0, stream>>>(qkv, att);
    gemm_bias_kernel<<<dim3(NC / 64, (NB * NT) / 64), blk, 0, stream>>>(
        att, Wproj, bproj, out, NB * NT, NC, NC);
}

// Round 4
// 481.813 us; speedup vs baseline: 2.9643x; 1.1627x over previous
//
#include <hip/hip_runtime.h>
#include <math.h>

#define NB 2
#define NT 4096
#define NC 512
#define NH 8
#define ND 64
#define N3C (3*NC)

typedef __attribute__((ext_vector_type(8))) __bf16 bf16x8;
typedef __attribute__((ext_vector_type(4))) __bf16 bf16x4;
typedef __attribute__((ext_vector_type(4))) float  f32x4;

// ---------------------------------------------------------------------------
// GEMM with bias: C[M,N] = A[M,K] @ B[K,N] + bias[N]  (fp32, unchanged)
// ---------------------------------------------------------------------------
__global__ __launch_bounds__(256) void gemm_bias_kernel(
    const float* __restrict__ A, const float* __restrict__ B,
    const float* __restrict__ bias, float* __restrict__ C,
    int M, int N, int K)
{
    __shared__ float As[16][65];
    __shared__ float Bs[16][64];

    const int tid = threadIdx.x;
    const int tx = tid & 15, ty = tid >> 4;
    const int r0 = ty << 2, c0 = tx << 2;
    const int m0 = blockIdx.y << 6, n0 = blockIdx.x << 6;
    const int ar = tid >> 2, ak = (tid & 3) << 2;
    const int br = tid >> 4, bc = (tid & 15) << 2;

    float acc[4][4] = {};

    for (int k0 = 0; k0 < K; k0 += 16) {
        float4 av = *(const float4*)(A + (size_t)(m0 + ar) * K + (k0 + ak));
        float4 bv = *(const float4*)(B + (size_t)(k0 + br) * N + (n0 + bc));
        __syncthreads();
        As[ak + 0][ar] = av.x;
        As[ak + 1][ar] = av.y;
        As[ak + 2][ar] = av.z;
        As[ak + 3][ar] = av.w;
        *(float4*)(&Bs[br][bc]) = bv;
        __syncthreads();
#pragma unroll
        for (int k = 0; k < 16; ++k) {
            const float a0 = As[k][r0 + 0];
            const float a1 = As[k][r0 + 1];
            const float a2 = As[k][r0 + 2];
            const float a3 = As[k][r0 + 3];
            const float4 bq = *(const float4*)(&Bs[k][c0]);
            acc[0][0] = fmaf(a0, bq.x, acc[0][0]); acc[0][1] = fmaf(a0, bq.y, acc[0][1]);
            acc[0][2] = fmaf(a0, bq.z, acc[0][2]); acc[0][3] = fmaf(a0, bq.w, acc[0][3]);
            acc[1][0] = fmaf(a1, bq.x, acc[1][0]); acc[1][1] = fmaf(a1, bq.y, acc[1][1]);
            acc[1][2] = fmaf(a1, bq.z, acc[1][2]); acc[1][3] = fmaf(a1, bq.w, acc[1][3]);
            acc[2][0] = fmaf(a2, bq.x, acc[2][0]); acc[2][1] = fmaf(a2, bq.y, acc[2][1]);
            acc[2][2] = fmaf(a2, bq.z, acc[2][2]); acc[2][3] = fmaf(a2, bq.w, acc[2][3]);
            acc[3][0] = fmaf(a3, bq.x, acc[3][0]); acc[3][1] = fmaf(a3, bq.y, acc[3][1]);
            acc[3][2] = fmaf(a3, bq.z, acc[3][2]); acc[3][3] = fmaf(a3, bq.w, acc[3][3]);
        }
    }

    const float4 bb = *(const float4*)(bias + n0 + c0);
#pragma unroll
    for (int i = 0; i < 4; ++i) {
        float4 cv = make_float4(acc[i][0] + bb.x, acc[i][1] + bb.y,
                                acc[i][2] + bb.z, acc[i][3] + bb.w);
        *(float4*)(C + (size_t)(m0 + r0 + i) * N + n0 + c0) = cv;
    }
}

// ---------------------------------------------------------------------------
// Causal flash attention, bf16 MFMA 16x16x32, fp32 softmax state.
// R4: BM=128 (8 waves), V column-gather staging (b64 LDS writes, no 16-way
// conflict), XOR-swizzled Ps (conflict-free write+read), K/V reg prefetch.
// ---------------------------------------------------------------------------
__global__ __launch_bounds__(512, 4) void attn_kernel(
    const float* __restrict__ qkv, float* __restrict__ out)
{
    __shared__ __bf16 QPs[128][72];  // Q tile, then reused as swizzled P tile
    __shared__ __bf16 Ks[64][72];    // [k-row][d]
    __shared__ __bf16 Vt[64][72];    // [d][k-row]

    const int tid  = threadIdx.x;
    const int qb   = 31 - blockIdx.x;          // big blocks first
    const int bh   = blockIdx.y;
    const int b    = bh >> 3, h = bh & 7;
    const int qr0  = qb << 7;
    const size_t base = (size_t)b * NT * N3C;
    const int col  = h * ND;

    const int w    = tid >> 6;                 // wave 0..7
    const int lane = tid & 63;
    const int g    = lane >> 4;
    const int n    = lane & 15;
    const int rb   = w << 4;                   // wave's q-row base (local)
    const int sw   = (g ^ (n >> 2)) << 3;      // swizzled P-frag halfword offset

    // K/Q staging geometry: rows rs(+32,..), cols cs..cs+3
    const int rs = tid >> 4;                   // 0..31
    const int cs = (tid & 15) << 2;
    // V column-gather geometry: lane = d, wave picks k-chunk
    const int vd = lane;
    const int vk = w << 2;                     // 0,4,...,28

    const float* kptr = qkv + base + NC + col + cs;
    const float* vptr = qkv + base + 2 * NC + col + vd;

    // ---- stage Q (pre-scaled by 0.125), fp32->bf16 ----
#pragma unroll
    for (int i = 0; i < 4; ++i) {
        const int r = rs + (i << 5);
        float4 v = *(const float4*)(qkv + base + (size_t)(qr0 + r) * N3C + col + cs);
        bf16x4 q;
        q[0] = (__bf16)(v.x * 0.125f);
        q[1] = (__bf16)(v.y * 0.125f);
        q[2] = (__bf16)(v.z * 0.125f);
        q[3] = (__bf16)(v.w * 0.125f);
        *(bf16x4*)&QPs[r][cs] = q;
    }
    __syncthreads();

    const bf16x8 qf0 = *(const bf16x8*)&QPs[rb + n][(g << 3)];
    const bf16x8 qf1 = *(const bf16x8*)&QPs[rb + n][32 + (g << 3)];

    bf16x8 ones;
#pragma unroll
    for (int j = 0; j < 8; ++j) ones[j] = (__bf16)1.0f;

    f32x4 O[4] = {{0.f,0.f,0.f,0.f},{0.f,0.f,0.f,0.f},{0.f,0.f,0.f,0.f},{0.f,0.f,0.f,0.f}};
    float m_i[4] = {-INFINITY, -INFINITY, -INFINITY, -INFINITY};
    float l_i[4] = {0.f, 0.f, 0.f, 0.f};

    // ---- preload tile 0 K/V ----
    float4 kreg0 = *(const float4*)(kptr + (size_t)rs * N3C);
    float4 kreg1 = *(const float4*)(kptr + (size_t)(rs + 32) * N3C);
    float vreg[8];
#pragma unroll
    for (int j = 0; j < 4; ++j) {
        vreg[j]     = vptr[(size_t)(vk + j) * N3C];
        vreg[4 + j] = vptr[(size_t)(vk + 32 + j) * N3C];
    }

    const int ntiles = (qb << 1) + 2;
    for (int jt = 0; jt < ntiles; ++jt) {
        __syncthreads();   // (A) everyone done reading prev Ks/Vt

        // prefetched regs -> LDS
        bf16x4 kc0, kc1, va, vb;
        kc0[0] = (__bf16)kreg0.x; kc0[1] = (__bf16)kreg0.y;
        kc0[2] = (__bf16)kreg0.z; kc0[3] = (__bf16)kreg0.w;
        kc1[0] = (__bf16)kreg1.x; kc1[1] = (__bf16)kreg1.y;
        kc1[2] = (__bf16)kreg1.z; kc1[3] = (__bf16)kreg1.w;
#pragma unroll
        for (int j = 0; j < 4; ++j) { va[j] = (__bf16)vreg[j]; vb[j] = (__bf16)vreg[4 + j]; }
        *(bf16x4*)&Ks[rs][cs]      = kc0;
        *(bf16x4*)&Ks[rs + 32][cs] = kc1;
        *(bf16x4*)&Vt[vd][vk]      = va;
        *(bf16x4*)&Vt[vd][vk + 32] = vb;
        __syncthreads();   // (B)

        // issue prefetch for next tile
        if (jt + 1 < ntiles) {
            const int kr1 = (jt + 1) << 6;
            kreg0 = *(const float4*)(kptr + (size_t)(kr1 + rs) * N3C);
            kreg1 = *(const float4*)(kptr + (size_t)(kr1 + rs + 32) * N3C);
#pragma unroll
            for (int j = 0; j < 4; ++j) {
                vreg[j]     = vptr[(size_t)(kr1 + vk + j) * N3C];
                vreg[4 + j] = vptr[(size_t)(kr1 + vk + 32 + j) * N3C];
            }
        }

        // ---- S = Q K^T ----
        f32x4 S[4];
#pragma unroll
        for (int t = 0; t < 4; ++t) {
            const bf16x8 k0 = *(const bf16x8*)&Ks[(t << 4) + n][(g << 3)];
            const bf16x8 k1 = *(const bf16x8*)&Ks[(t << 4) + n][32 + (g << 3)];
            f32x4 acc = {0.f, 0.f, 0.f, 0.f};
            acc = __builtin_amdgcn_mfma_f32_16x16x32_bf16(qf0, k0, acc, 0, 0, 0);
            acc = __builtin_amdgcn_mfma_f32_16x16x32_bf16(qf1, k1, acc, 0, 0, 0);
            S[t] = acc;
        }

        // ---- causal mask (last two tiles only) ----
        if (jt >= (qb << 1)) {
            const int kg0 = (jt << 6) - qr0 - rb - (g << 2);  // col - row offset
#pragma unroll
            for (int t = 0; t < 4; ++t)
#pragma unroll
                for (int reg = 0; reg < 4; ++reg)
                    if (kg0 + (t << 4) + n > reg) S[t][reg] = -INFINITY;
        }

        // ---- online softmax (row-max shuffles; row-sum via MFMA) ----
        float mnew[4], alpha[4];
#pragma unroll
        for (int reg = 0; reg < 4; ++reg) {
            float mx = fmaxf(fmaxf(S[0][reg], S[1][reg]), fmaxf(S[2][reg], S[3][reg]));
            mx = fmaxf(mx, __shfl_xor(mx, 1));
            mx = fmaxf(mx, __shfl_xor(mx, 2));
            mx = fmaxf(mx, __shfl_xor(mx, 4));
            mx = fmaxf(mx, __shfl_xor(mx, 8));
            mnew[reg]  = fmaxf(m_i[reg], mx);
            alpha[reg] = __expf(m_i[reg] - mnew[reg]);
            m_i[reg]   = mnew[reg];
        }
#pragma unroll
        for (int t = 0; t < 4; ++t)
#pragma unroll
            for (int reg = 0; reg < 4; ++reg)
                S[t][reg] = __expf(S[t][reg] - mnew[reg]);

        // stage P swizzled (phys col = col ^ 8g); same-wave rows only
#pragma unroll
        for (int t = 0; t < 4; ++t)
#pragma unroll
            for (int reg = 0; reg < 4; ++reg)
                QPs[rb + (g << 2) + reg][((t << 4) + n) ^ (g << 3)] = (__bf16)S[t][reg];

#pragma unroll
        for (int t = 0; t < 4; ++t)
#pragma unroll
            for (int reg = 0; reg < 4; ++reg)
                O[t][reg] *= alpha[reg];

        // ---- O += P V ; l += P * ones ----
        const bf16x8 p0 = *(const bf16x8*)&QPs[rb + n][sw];
        const bf16x8 p1 = *(const bf16x8*)&QPs[rb + n][32 + sw];
        f32x4 Lacc = {0.f, 0.f, 0.f, 0.f};
        Lacc = __builtin_amdgcn_mfma_f32_16x16x32_bf16(p0, ones, Lacc, 0, 0, 0);
        Lacc = __builtin_amdgcn_mfma_f32_16x16x32_bf16(p1, ones, Lacc, 0, 0, 0);
#pragma unroll
        for (int t = 0; t < 4; ++t) {
            const bf16x8 v0 = *(const bf16x8*)&Vt[(t << 4) + n][(g << 3)];
            const bf16x8 v1 = *(const bf16x8*)&Vt[(t << 4) + n][32 + (g << 3)];
            O[t] = __builtin_amdgcn_mfma_f32_16x16x32_bf16(p0, v0, O[t], 0, 0, 0);
            O[t] = __builtin_amdgcn_mfma_f32_16x16x32_bf16(p1, v1, O[t], 0, 0, 0);
        }
#pragma unroll
        for (int reg = 0; reg < 4; ++reg)
            l_i[reg] = alpha[reg] * l_i[reg] + Lacc[reg];
    }

    // ---- epilogue ----
#pragma unroll
    for (int reg = 0; reg < 4; ++reg) {
        const float inv = 1.0f / l_i[reg];
        const size_t row = (size_t)b * NT + qr0 + rb + (g << 2) + reg;
#pragma unroll
        for (int t = 0; t < 4; ++t)
            out[row * NC + col + (t << 4) + n] = O[t][reg] * inv;
    }
}

// ---------------------------------------------------------------------------
extern "C" void kernel_launch(void* const* d_in, const int* in_sizes, int n_in,
                              void* d_out, int out_size, void* d_ws, size_t ws_size,
                              hipStream_t stream)
{
    const float* x     = (const float*)d_in[0];
    const float* Wqkv  = (const float*)d_in[1];
    const float* bqkv  = (const float*)d_in[2];
    const float* Wproj = (const float*)d_in[3];
    const float* bproj = (const float*)d_in[4];
    float* out = (float*)d_out;

    float* qkv = (float*)d_ws;                         // [B,T,3C] fp32
    float* att = qkv + (size_t)NB * NT * N3C;          // [B,T,C]  fp32

    gemm_bias_kernel<<<dim3(N3C / 64, (NB * NT) / 64), dim3(256), 0, stream>>>(
        x, Wqkv, bqkv, qkv, NB * NT, N3C, NC);
    attn_kernel<<<dim3(NT / 128, NB * NH), dim3(512), 0, stream>>>(qkv, att);
    gemm_bias_kernel<<<dim3(NC / 64, (NB * NT) / 64), dim3(256), 0, stream>>>(
        att, Wproj, bproj, out, NB * NT, NC, NC);
}

// Round 5
// 287.801 us; speedup vs baseline: 4.9626x; 1.6741x over previous
//
#include <hip/hip_runtime.h>
#include <math.h>

#define NB 2
#define NT 4096
#define NC 512
#define NH 8
#define ND 64
#define N3C (3*NC)

typedef __attribute__((ext_vector_type(8))) __bf16 bf16x8;
typedef __attribute__((ext_vector_type(4))) __bf16 bf16x4;
typedef __attribute__((ext_vector_type(4))) float  f32x4;

// ---------------------------------------------------------------------------
// fp32 -> bf16 elementwise (x)
// ---------------------------------------------------------------------------
__global__ __launch_bounds__(256) void cvt_bf16_kernel(
    const float* __restrict__ x, __bf16* __restrict__ xb, int n)
{
    const int i = (blockIdx.x * 256 + threadIdx.x) << 3;
    if (i < n) {
        float4 a = *(const float4*)(x + i);
        float4 b = *(const float4*)(x + i + 4);
        bf16x8 o;
        o[0] = (__bf16)a.x; o[1] = (__bf16)a.y; o[2] = (__bf16)a.z; o[3] = (__bf16)a.w;
        o[4] = (__bf16)b.x; o[5] = (__bf16)b.y; o[6] = (__bf16)b.z; o[7] = (__bf16)b.w;
        *(bf16x8*)(xb + i) = o;
    }
}

// ---------------------------------------------------------------------------
// W[K][N] fp32 -> Wt[N][K] bf16 (transpose + convert), 64x64 LDS tiles
// ---------------------------------------------------------------------------
__global__ __launch_bounds__(256) void transpose_cvt_kernel(
    const float* __restrict__ W, __bf16* __restrict__ Wt, int K, int N)
{
    __shared__ float T[64][65];
    const int n0 = blockIdx.x << 6, k0 = blockIdx.y << 6;
    const int tx = threadIdx.x & 15, ty = threadIdx.x >> 4;
#pragma unroll
    for (int i = 0; i < 4; ++i) {
        const int r = ty + (i << 4);
        float4 v = *(const float4*)(W + (size_t)(k0 + r) * N + n0 + (tx << 2));
        T[r][(tx << 2) + 0] = v.x;
        T[r][(tx << 2) + 1] = v.y;
        T[r][(tx << 2) + 2] = v.z;
        T[r][(tx << 2) + 3] = v.w;
    }
    __syncthreads();
#pragma unroll
    for (int i = 0; i < 4; ++i) {
        const int nr = ty + (i << 4);
        bf16x4 o;
        o[0] = (__bf16)T[(tx << 2) + 0][nr];
        o[1] = (__bf16)T[(tx << 2) + 1][nr];
        o[2] = (__bf16)T[(tx << 2) + 2][nr];
        o[3] = (__bf16)T[(tx << 2) + 3][nr];
        *(bf16x4*)(Wt + (size_t)(n0 + nr) * K + k0 + (tx << 2)) = o;
    }
}

// ---------------------------------------------------------------------------
// bf16 MFMA GEMM: C[M][N] = A[M][K] @ Bt[N][K]^T + bias[N]
// 128x128 tile, BK=32, 256 thr / 4 waves, 64x64 per wave, reg prefetch.
// out_bf16: store __bf16, else float.
// ---------------------------------------------------------------------------
__global__ __launch_bounds__(256) void gemm_bf16_kernel(
    const __bf16* __restrict__ A, const __bf16* __restrict__ Bt,
    const float* __restrict__ bias, void* __restrict__ Cout,
    int M, int N, int K, int out_bf16)
{
    __shared__ __bf16 As[128][40];
    __shared__ __bf16 Bs[128][40];

    const int tid  = threadIdx.x;
    const int w    = tid >> 6, lane = tid & 63;
    const int g    = lane >> 4, n = lane & 15;
    const int wr   = (w >> 1) << 6;   // wave row offset: 0/64
    const int wc   = (w & 1) << 6;    // wave col offset: 0/64
    const int m0   = blockIdx.y << 7, n0 = blockIdx.x << 7;

    // staging: thread -> row sr (0..127), k-chunk sh (0 or 16)
    const int sr = tid >> 1;
    const int sh = (tid & 1) << 4;
    const __bf16* ap = A  + (size_t)(m0 + sr) * K + sh;
    const __bf16* bp = Bt + (size_t)(n0 + sr) * K + sh;

    f32x4 acc[4][4];
#pragma unroll
    for (int i = 0; i < 4; ++i)
#pragma unroll
        for (int j = 0; j < 4; ++j) acc[i][j] = (f32x4){0.f, 0.f, 0.f, 0.f};

    bf16x8 a0 = *(const bf16x8*)ap;
    bf16x8 a1 = *(const bf16x8*)(ap + 8);
    bf16x8 b0 = *(const bf16x8*)bp;
    bf16x8 b1 = *(const bf16x8*)(bp + 8);

    const int ksteps = K >> 5;
    for (int ks = 0; ks < ksteps; ++ks) {
        __syncthreads();
        *(bf16x8*)&As[sr][sh]     = a0;
        *(bf16x8*)&As[sr][sh + 8] = a1;
        *(bf16x8*)&Bs[sr][sh]     = b0;
        *(bf16x8*)&Bs[sr][sh + 8] = b1;
        __syncthreads();

        if (ks + 1 < ksteps) {
            const int ko = (ks + 1) << 5;
            a0 = *(const bf16x8*)(ap + ko);
            a1 = *(const bf16x8*)(ap + ko + 8);
            b0 = *(const bf16x8*)(bp + ko);
            b1 = *(const bf16x8*)(bp + ko + 8);
        }

        bf16x8 af[4], bf[4];
#pragma unroll
        for (int i = 0; i < 4; ++i) {
            af[i] = *(const bf16x8*)&As[wr + (i << 4) + n][g << 3];
            bf[i] = *(const bf16x8*)&Bs[wc + (i << 4) + n][g << 3];
        }
#pragma unroll
        for (int i = 0; i < 4; ++i)
#pragma unroll
            for (int j = 0; j < 4; ++j)
                acc[i][j] = __builtin_amdgcn_mfma_f32_16x16x32_bf16(af[i], bf[j], acc[i][j], 0, 0, 0);
    }

    // epilogue: + bias, store
#pragma unroll
    for (int j = 0; j < 4; ++j) {
        const int colg = n0 + wc + (j << 4) + n;
        const float bb = bias[colg];
#pragma unroll
        for (int i = 0; i < 4; ++i) {
#pragma unroll
            for (int reg = 0; reg < 4; ++reg) {
                const int rowg = m0 + wr + (i << 4) + (g << 2) + reg;
                const float v = acc[i][j][reg] + bb;
                if (out_bf16)
                    ((__bf16*)Cout)[(size_t)rowg * N + colg] = (__bf16)v;
                else
                    ((float*)Cout)[(size_t)rowg * N + colg] = v;
            }
        }
    }
}

// ---------------------------------------------------------------------------
// Causal flash attention, bf16 in/out, bf16 MFMA 16x16x32, fp32 softmax.
// BM=128 (8 waves), V column-gather, XOR-swizzled Ps, K/V reg prefetch.
// ---------------------------------------------------------------------------
__global__ __launch_bounds__(512, 4) void attn_kernel(
    const __bf16* __restrict__ qkv, __bf16* __restrict__ out)
{
    __shared__ __bf16 QPs[128][72];
    __shared__ __bf16 Ks[64][72];
    __shared__ __bf16 Vt[64][72];

    const int tid  = threadIdx.x;
    const int qb   = 31 - blockIdx.x;
    const int bh   = blockIdx.y;
    const int b    = bh >> 3, h = bh & 7;
    const int qr0  = qb << 7;
    const size_t base = (size_t)b * NT * N3C;
    const int col  = h * ND;

    const int w    = tid >> 6;
    const int lane = tid & 63;
    const int g    = lane >> 4;
    const int n    = lane & 15;
    const int rb   = w << 4;
    const int sw   = (g ^ (n >> 2)) << 3;

    // K/Q staging: row kr (0..63), col chunk kc (8 bf16)
    const int kr = tid >> 3;
    const int kc = (tid & 7) << 3;
    // V column-gather: lane = d, wave picks k-chunk
    const int vd = lane;
    const int vk = w << 2;

    const __bf16* kptr = qkv + base + NC + col + kc;
    const __bf16* vptr = qkv + base + 2 * NC + col + vd;

    // ---- stage Q (pre-scaled by 0.125) ----
#pragma unroll
    for (int i = 0; i < 2; ++i) {
        const int r = kr + (i << 6);
        bf16x8 v = *(const bf16x8*)(qkv + base + (size_t)(qr0 + r) * N3C + col + kc);
        bf16x8 q;
#pragma unroll
        for (int j = 0; j < 8; ++j) q[j] = (__bf16)(0.125f * (float)v[j]);
        *(bf16x8*)&QPs[r][kc] = q;
    }
    __syncthreads();

    const bf16x8 qf0 = *(const bf16x8*)&QPs[rb + n][(g << 3)];
    const bf16x8 qf1 = *(const bf16x8*)&QPs[rb + n][32 + (g << 3)];

    bf16x8 ones;
#pragma unroll
    for (int j = 0; j < 8; ++j) ones[j] = (__bf16)1.0f;

    f32x4 O[4] = {{0.f,0.f,0.f,0.f},{0.f,0.f,0.f,0.f},{0.f,0.f,0.f,0.f},{0.f,0.f,0.f,0.f}};
    float m_i[4] = {-INFINITY, -INFINITY, -INFINITY, -INFINITY};
    float l_i[4] = {0.f, 0.f, 0.f, 0.f};

    // ---- preload tile 0 ----
    bf16x8 kreg = *(const bf16x8*)(kptr + (size_t)kr * N3C);
    __bf16 vreg[8];
#pragma unroll
    for (int j = 0; j < 4; ++j) {
        vreg[j]     = vptr[(size_t)(vk + j) * N3C];
        vreg[4 + j] = vptr[(size_t)(vk + 32 + j) * N3C];
    }

    const int ntiles = (qb << 1) + 2;
    for (int jt = 0; jt < ntiles; ++jt) {
        __syncthreads();
        *(bf16x8*)&Ks[kr][kc] = kreg;
        {
            bf16x4 va, vb;
#pragma unroll
            for (int j = 0; j < 4; ++j) { va[j] = vreg[j]; vb[j] = vreg[4 + j]; }
            *(bf16x4*)&Vt[vd][vk]      = va;
            *(bf16x4*)&Vt[vd][vk + 32] = vb;
        }
        __syncthreads();

        if (jt + 1 < ntiles) {
            const int kr1 = (jt + 1) << 6;
            kreg = *(const bf16x8*)(kptr + (size_t)(kr1 + kr) * N3C);
#pragma unroll
            for (int j = 0; j < 4; ++j) {
                vreg[j]     = vptr[(size_t)(kr1 + vk + j) * N3C];
                vreg[4 + j] = vptr[(size_t)(kr1 + vk + 32 + j) * N3C];
            }
        }

        // ---- S = Q K^T ----
        f32x4 S[4];
#pragma unroll
        for (int t = 0; t < 4; ++t) {
            const bf16x8 k0 = *(const bf16x8*)&Ks[(t << 4) + n][(g << 3)];
            const bf16x8 k1 = *(const bf16x8*)&Ks[(t << 4) + n][32 + (g << 3)];
            f32x4 a = {0.f, 0.f, 0.f, 0.f};
            a = __builtin_amdgcn_mfma_f32_16x16x32_bf16(qf0, k0, a, 0, 0, 0);
            a = __builtin_amdgcn_mfma_f32_16x16x32_bf16(qf1, k1, a, 0, 0, 0);
            S[t] = a;
        }

        // ---- causal mask (last two tiles) ----
        if (jt >= (qb << 1)) {
            const int kg0 = (jt << 6) - qr0 - rb - (g << 2);
#pragma unroll
            for (int t = 0; t < 4; ++t)
#pragma unroll
                for (int reg = 0; reg < 4; ++reg)
                    if (kg0 + (t << 4) + n > reg) S[t][reg] = -INFINITY;
        }

        // ---- online softmax ----
        float mnew[4], alpha[4];
#pragma unroll
        for (int reg = 0; reg < 4; ++reg) {
            float mx = fmaxf(fmaxf(S[0][reg], S[1][reg]), fmaxf(S[2][reg], S[3][reg]));
            mx = fmaxf(mx, __shfl_xor(mx, 1));
            mx = fmaxf(mx, __shfl_xor(mx, 2));
            mx = fmaxf(mx, __shfl_xor(mx, 4));
            mx = fmaxf(mx, __shfl_xor(mx, 8));
            mnew[reg]  = fmaxf(m_i[reg], mx);
            alpha[reg] = __expf(m_i[reg] - mnew[reg]);
            m_i[reg]   = mnew[reg];
        }
#pragma unroll
        for (int t = 0; t < 4; ++t)
#pragma unroll
            for (int reg = 0; reg < 4; ++reg)
                S[t][reg] = __expf(S[t][reg] - mnew[reg]);

#pragma unroll
        for (int t = 0; t < 4; ++t)
#pragma unroll
            for (int reg = 0; reg < 4; ++reg)
                QPs[rb + (g << 2) + reg][((t << 4) + n) ^ (g << 3)] = (__bf16)S[t][reg];

#pragma unroll
        for (int t = 0; t < 4; ++t)
#pragma unroll
            for (int reg = 0; reg < 4; ++reg)
                O[t][reg] *= alpha[reg];

        const bf16x8 p0 = *(const bf16x8*)&QPs[rb + n][sw];
        const bf16x8 p1 = *(const bf16x8*)&QPs[rb + n][32 + sw];
        f32x4 Lacc = {0.f, 0.f, 0.f, 0.f};
        Lacc = __builtin_amdgcn_mfma_f32_16x16x32_bf16(p0, ones, Lacc, 0, 0, 0);
        Lacc = __builtin_amdgcn_mfma_f32_16x16x32_bf16(p1, ones, Lacc, 0, 0, 0);
#pragma unroll
        for (int t = 0; t < 4; ++t) {
            const bf16x8 v0 = *(const bf16x8*)&Vt[(t << 4) + n][(g << 3)];
            const bf16x8 v1 = *(const bf16x8*)&Vt[(t << 4) + n][32 + (g << 3)];
            O[t] = __builtin_amdgcn_mfma_f32_16x16x32_bf16(p0, v0, O[t], 0, 0, 0);
            O[t] = __builtin_amdgcn_mfma_f32_16x16x32_bf16(p1, v1, O[t], 0, 0, 0);
        }
#pragma unroll
        for (int reg = 0; reg < 4; ++reg)
            l_i[reg] = alpha[reg] * l_i[reg] + Lacc[reg];
    }

    // ---- epilogue: bf16 store ----
#pragma unroll
    for (int reg = 0; reg < 4; ++reg) {
        const float inv = 1.0f / l_i[reg];
        const size_t row = (size_t)b * NT + qr0 + rb + (g << 2) + reg;
#pragma unroll
        for (int t = 0; t < 4; ++t)
            out[row * NC + col + (t << 4) + n] = (__bf16)(O[t][reg] * inv);
    }
}

// ---------------------------------------------------------------------------
extern "C" void kernel_launch(void* const* d_in, const int* in_sizes, int n_in,
                              void* d_out, int out_size, void* d_ws, size_t ws_size,
                              hipStream_t stream)
{
    const float* x     = (const float*)d_in[0];
    const float* Wqkv  = (const float*)d_in[1];
    const float* bqkv  = (const float*)d_in[2];
    const float* Wproj = (const float*)d_in[3];
    const float* bproj = (const float*)d_in[4];
    float* out = (float*)d_out;

    // workspace carve (bytes, 256-aligned)
    char* ws = (char*)d_ws;
    __bf16* xb     = (__bf16*)(ws);                    //  8.0 MB  [8192][512]
    __bf16* qkvb   = (__bf16*)(ws + 8388608);          // 24.0 MB  [8192][1536]
    __bf16* attb   = (__bf16*)(ws + 33554432);         //  8.0 MB  [8192][512]
    __bf16* wqkvt  = (__bf16*)(ws + 41943040);         //  1.5 MB  [1536][512]
    __bf16* wprojt = (__bf16*)(ws + 43515904);         //  0.5 MB  [512][512]

    // convert / transpose inputs
    cvt_bf16_kernel<<<dim3(2048), dim3(256), 0, stream>>>(x, xb, NB * NT * NC);
    transpose_cvt_kernel<<<dim3(N3C / 64, NC / 64), dim3(256), 0, stream>>>(
        Wqkv, wqkvt, NC, N3C);
    transpose_cvt_kernel<<<dim3(NC / 64, NC / 64), dim3(256), 0, stream>>>(
        Wproj, wprojt, NC, NC);

    // qkv = x @ Wqkv + bqkv   (bf16 out)
    gemm_bf16_kernel<<<dim3(N3C / 128, (NB * NT) / 128), dim3(256), 0, stream>>>(
        xb, wqkvt, bqkv, qkvb, NB * NT, N3C, NC, 1);
    // attention
    attn_kernel<<<dim3(NT / 128, NB * NH), dim3(512), 0, stream>>>(qkvb, attb);
    // out = att @ Wproj + bproj   (fp32 out)
    gemm_bf16_kernel<<<dim3(NC / 128, (NB * NT) / 128), dim3(256), 0, stream>>>(
        attb, wprojt, bproj, out, NB * NT, NC, NC, 0);
}